// Round 3
// baseline (280.263 us; speedup 1.0000x reference)
//
#include <hip/hip_runtime.h>
#include <math.h>

// Capsule routing, u_hat never materialized (factors through W):
//   v[b,n,c] = sum_i c[b,n,i] u[b,i,c]
//   s[b,n,d] = sum_c v[b,n,c] W[c,n*64+d];  o = squash(s)
//   t[b,n,c] = sum_d o[b,n,d] W[c,n*64+d]
//   b[b,n,i] = sum_c t[b,n,c] u[b,i,c]
// Iter 0: b=0 -> c uniform 1/32 -> v0 = colsum(u)/32.
//
// R12: launch-count round. 6 -> 4 kernels. Each route+sst pair fused via a
// last-arrival protocol (rocPRIM-style): route blocks (b,it) store their bf16
// pv slab, __syncthreads (drains vmcnt -> L2), tid0 __threadfence (L2 wb) and
// increments 8 per-b counters (one per 4-n group); increment returning 31
// makes this block the winner for that n-group. Winner does an acquire
// __threadfence (L2 inv; cross-XCD safety, G16) then computes sst for its 4 n
// (one wave per n): v = sum of 32 it-slabs, s = v.Wslice, squash, t (or out).
// Counters zeroed in k_pre (kernel-boundary ordered, re-zeroed each replay).
// Winner identity nondeterministic; tail math winner-independent -> output
// deterministic. Carried: ub16 precast, bf16 W both layouts, bf16 pv, bf16 t,
// vectorized k_sst (iter0 only), MFMA route, no grid.sync (R4: 1000us spin).

constexpr int Bn = 32, In = 1024, Cn = 256, Nn = 32, Dn = 64, ND = 2048;

typedef __attribute__((ext_vector_type(8))) short bf16x8;
typedef __attribute__((ext_vector_type(4))) float f32x4;

__device__ __forceinline__ unsigned int packbf2(float a, float b) {
  unsigned int xa = __float_as_uint(a), xb = __float_as_uint(b);
  xa = (xa + 0x7fffu + ((xa >> 16) & 1u)) >> 16;  // RNE
  xb = (xb + 0x7fffu + ((xb >> 16) & 1u)) >> 16;
  return xa | (xb << 16);
}
__device__ __forceinline__ unsigned short packbf1(float a) {
  unsigned int x = __float_as_uint(a);
  return (unsigned short)((x + 0x7fffu + ((x >> 16) & 1u)) >> 16);
}
__device__ __forceinline__ float bfu(unsigned short us) {
  return __uint_as_float((unsigned int)us << 16);
}

// ---- k_pre: colsum+ucast (z<1024) | WbfT transpose | Wbf cast | cnt zero ---
__global__ __launch_bounds__(256) void k_pre(
    const float* __restrict__ u, const float* __restrict__ W,
    float* __restrict__ psu, unsigned short* __restrict__ Wbf,
    unsigned short* __restrict__ WbfT, unsigned short* __restrict__ ub16,
    unsigned int* __restrict__ cnt) {
  const int z = blockIdx.x, tid = threadIdx.x;
  if (z < 1024) {  // colsum: psu[z*256+c] = sum over 32 i of u[b, ch*32+i, c]
    int b = z >> 5, ch = z & 31;
    const float* up = u + ((size_t)(b * In + ch * 32)) * Cn + tid;
    unsigned short* ubp = ub16 + ((size_t)(b * In + ch * 32)) * Cn + tid;
    float s = 0.f;
#pragma unroll 8
    for (int j = 0; j < 32; ++j) {
      float v = up[(size_t)j * Cn];
      s += v;
      ubp[(size_t)j * Cn] = packbf1(v);  // bf16 u copy, coalesced 512B rows
    }
    psu[(size_t)z * Cn + tid] = s;
  } else if (z < 1152) {  // WbfT[nd][c] = bf16(W[c][nd]), 64x64 tiles
    __shared__ float tile[64][65];
    int t = z - 1024;
    int x0 = (t & 31) * 64, y0 = (t >> 5) * 64;  // x=nd, y=c
    int lx = tid & 63, ly = tid >> 6;
#pragma unroll
    for (int k = 0; k < 16; ++k) {
      int y = ly + k * 4;
      tile[y][lx] = W[(size_t)(y0 + y) * ND + x0 + lx];
    }
    __syncthreads();
#pragma unroll
    for (int k = 0; k < 8; ++k) {  // 64 rows x 32 uints
      int idx = tid + k * 256;
      int row = idx >> 5, cu = idx & 31;
      unsigned int v = packbf2(tile[2 * cu][row], tile[2 * cu + 1][row]);
      *(unsigned int*)&WbfT[(size_t)(x0 + row) * Cn + y0 + 2 * cu] = v;
    }
  } else {  // Wbf: straight cast, 128 blocks x 4096 floats
    int zb = z - 1152;
    if (zb == 0) { cnt[tid] = 0u; cnt[256 + tid] = 0u; }  // zero both sets
    const float* src = W + (size_t)zb * 4096;
    unsigned short* dst = Wbf + (size_t)zb * 4096;
#pragma unroll
    for (int k = 0; k < 4; ++k) {
      int off = k * 1024 + tid * 4;
      const float4 v = *(const float4*)&src[off];
      *(uint2*)&dst[off] = make_uint2(packbf2(v.x, v.y), packbf2(v.z, v.w));
    }
  }
}

// ---- k_sst: iter-0 only (v0 = colsum/32, same for all n of a b) ------------
__global__ __launch_bounds__(256) void k_sst(
    const float* __restrict__ psu, float scale,
    const unsigned short* __restrict__ Wbf,
    const unsigned short* __restrict__ WbfT, unsigned short* __restrict__ tb) {
  int bn = blockIdx.x, b = bn >> 5, n = bn & 31;
  int tid = threadIdx.x;
  __shared__ float vs[Cn];
  __shared__ float ol[Dn];
  __shared__ float scr[2176];  // phase1/3: [8][272]; phase2: [32][68]
  {  // phase 1a: v partials. thread (g=tid>>5 -> 4 ch, co=tid&31 -> 8 c)
    const int g = tid >> 5, co = tid & 31;
    float acc[8];
#pragma unroll
    for (int e = 0; e < 8; ++e) acc[e] = 0.f;
    const float* p = psu + (size_t)b * 8192 + co * 8;
#pragma unroll
    for (int k = 0; k < 4; ++k) {
      const float4 v0 = *(const float4*)&p[(size_t)(g * 4 + k) * 256];
      const float4 v1 = *(const float4*)&p[(size_t)(g * 4 + k) * 256 + 4];
      acc[0] += v0.x; acc[1] += v0.y; acc[2] += v0.z; acc[3] += v0.w;
      acc[4] += v1.x; acc[5] += v1.y; acc[6] += v1.z; acc[7] += v1.w;
    }
    *(float4*)&scr[g * 272 + co * 8] =
        make_float4(acc[0], acc[1], acc[2], acc[3]);
    *(float4*)&scr[g * 272 + co * 8 + 4] =
        make_float4(acc[4], acc[5], acc[6], acc[7]);
  }
  __syncthreads();
  {  // phase 1b: vs[c] = sum of 8 partials
    float s = 0.f;
#pragma unroll
    for (int k = 0; k < 8; ++k) s += scr[k * 272 + tid];
    vs[tid] = s * scale;
  }
  __syncthreads();
  {  // phase 2: s partials. thread (cg=tid>>3 -> 8 c, do8=tid&7 -> 8 d)
    const int cg = tid >> 3, do8 = tid & 7;
    const unsigned short* wp =
        Wbf + (size_t)(cg * 8) * ND + (size_t)n * Dn + do8 * 8;
    float acc[8];
#pragma unroll
    for (int e = 0; e < 8; ++e) acc[e] = 0.f;
#pragma unroll
    for (int j = 0; j < 8; ++j) {
      union { bf16x8 v; unsigned short us[8]; } w;
      w.v = *(const bf16x8*)&wp[(size_t)j * ND];
      const float vc = vs[cg * 8 + j];
#pragma unroll
      for (int e = 0; e < 8; ++e) acc[e] += vc * bfu(w.us[e]);
    }
    *(float4*)&scr[cg * 68 + do8 * 8] =
        make_float4(acc[0], acc[1], acc[2], acc[3]);
    *(float4*)&scr[cg * 68 + do8 * 8 + 4] =
        make_float4(acc[4], acc[5], acc[6], acc[7]);
  }
  __syncthreads();
  if (tid < 64) {  // squash (one full wave): sum 32 cg partials per d
    float a = 0.f;
#pragma unroll
    for (int k = 0; k < 32; ++k) a += scr[k * 68 + tid];
    float sq = a * a;
#pragma unroll
    for (int off = 32; off > 0; off >>= 1) sq += __shfl_xor(sq, off, 64);
    ol[tid] = a / sqrtf(sq + 1e-7f);
  }
  __syncthreads();
  {  // phase 3: t partials. thread (dg=tid>>5 -> 8 d, co -> 8 c)
    const int dg = tid >> 5, co = tid & 31;
    const unsigned short* wt = WbfT + (size_t)(n * Dn + dg * 8) * Cn + co * 8;
    float acc[8];
#pragma unroll
    for (int e = 0; e < 8; ++e) acc[e] = 0.f;
#pragma unroll
    for (int e = 0; e < 8; ++e) {
      union { bf16x8 v; unsigned short us[8]; } w;
      w.v = *(const bf16x8*)&wt[(size_t)e * Cn];
      const float od = ol[dg * 8 + e];
#pragma unroll
      for (int cc = 0; cc < 8; ++cc) acc[cc] += od * bfu(w.us[cc]);
    }
    *(float4*)&scr[dg * 272 + co * 8] =
        make_float4(acc[0], acc[1], acc[2], acc[3]);
    *(float4*)&scr[dg * 272 + co * 8 + 4] =
        make_float4(acc[4], acc[5], acc[6], acc[7]);
  }
  __syncthreads();
  {
    float s = 0.f;
#pragma unroll
    for (int k = 0; k < 8; ++k) s += scr[k * 272 + tid];
    tb[(size_t)bn * Cn + tid] = packbf1(s);  // t stored bf16
  }
}

// ---- fused route+sst: bb -> softmax -> pv, then winner blocks do sst -------
// Block (b, it). After pv slab store: fence + 8 per-b group counters; winner
// of group g computes sst for n = g*4 .. g*4+3 (one wave per n).
__global__ __launch_bounds__(256, 4) void k_route_f(
    const unsigned short* __restrict__ tbb,
    const unsigned short* __restrict__ ub16,
    unsigned short* __restrict__ pvb,
    const unsigned short* __restrict__ Wbf,
    const unsigned short* __restrict__ WbfT,
    unsigned short* __restrict__ t16_out, float* __restrict__ outp,
    int writeT, unsigned int* __restrict__ cnt) {
  const int b = blockIdx.x, itile = blockIdx.y, i0 = itile * 32;
  const int tid = threadIdx.x;
  const int lane = tid & 63, w = tid >> 6;
  const int mrow = lane & 15, quad = lane >> 4;

  __shared__ unsigned short t_l[32][264];   // bf16; row 528 B; reused as pvs
  __shared__ unsigned short u_t[256][40];   // bf16 i-major; row 80 B
  __shared__ unsigned short cm_l[32][40];   // bf16 softmax(c)
  __shared__ float bb_l[32][36];
  __shared__ float smr[2][8][32];           // softmax partial max / sum
  __shared__ unsigned int gmask;
  __shared__ float vvL[4][256];             // tail: v per wave's n
  __shared__ float olL[4][64];              // tail: squash output

  // ---- stage t (straight bf16 copy) + u_t (bf16 copy, transposed) ----
  {
    const unsigned short* tp = tbb + (size_t)b * Nn * Cn;
#pragma unroll
    for (int k = 0; k < 8; ++k) {
      int idx = tid + k * 256;           // 2048 = 32 rows x 64 quads
      int row = idx >> 6, q = idx & 63;
      *(uint2*)&t_l[row][q * 4] = *(const uint2*)&tp[(size_t)row * Cn + q * 4];
    }
    const int ti = tid & 31, qb = tid >> 5;
    const unsigned short* up = ub16 + ((size_t)(b * In + i0 + ti)) * Cn;
#pragma unroll
    for (int m = 0; m < 4; ++m) {
      int c8 = qb + m * 8;               // chunk of 8 consecutive c
      union { bf16x8 v; unsigned short us[8]; } uv;
      uv.v = *(const bf16x8*)&up[c8 * 8];
#pragma unroll
      for (int e = 0; e < 8; ++e) u_t[c8 * 8 + e][ti] = uv.us[e];
    }
  }
  __syncthreads();

  // ---- phase A: D[i,n] = sum_c u[i,c] t[n,c]; wave tile (i0t, n0t) ----
  {
    const int i0t = (w & 1) * 16, n0t = (w >> 1) * 16;
    const unsigned short* ubp =
        ub16 + ((size_t)(b * In + i0 + i0t + mrow)) * Cn + quad * 8;
    f32x4 acc = {0.f, 0.f, 0.f, 0.f};
#pragma unroll
    for (int k0 = 0; k0 < 8; ++k0) {       // c = k0*32 + quad*8 + j
      const bf16x8 af = *(const bf16x8*)(ubp + k0 * 32);
      const bf16x8 bf = *(const bf16x8*)&t_l[n0t + mrow][k0 * 32 + quad * 8];
      acc = __builtin_amdgcn_mfma_f32_16x16x32_bf16(af, bf, acc, 0, 0, 0);
    }
#pragma unroll
    for (int r = 0; r < 4; ++r)
      bb_l[n0t + mrow][i0t + quad * 4 + r] = acc[r];
  }
  __syncthreads();

  // ---- softmax over n per i (wave-parallel: thread (g=tid>>5, i=tid&31)) --
  {
    const int i = tid & 31, g = tid >> 5;  // g handles n = g*4 .. g*4+3
    float m4 = bb_l[g * 4 + 0][i];
    m4 = fmaxf(m4, bb_l[g * 4 + 1][i]);
    m4 = fmaxf(m4, bb_l[g * 4 + 2][i]);
    m4 = fmaxf(m4, bb_l[g * 4 + 3][i]);
    smr[0][g][i] = m4;
    __syncthreads();
    float m = smr[0][0][i];
#pragma unroll
    for (int k = 1; k < 8; ++k) m = fmaxf(m, smr[0][k][i]);
    float s4 = 0.f;
#pragma unroll
    for (int r = 0; r < 4; ++r) {
      float e = __expf(bb_l[g * 4 + r][i] - m);
      bb_l[g * 4 + r][i] = e;
      s4 += e;
    }
    smr[1][g][i] = s4;
    __syncthreads();
    float ss = 0.f;
#pragma unroll
    for (int k = 0; k < 8; ++k) ss += smr[1][k][i];
    float inv = 1.f / ss;
#pragma unroll
    for (int r = 0; r < 4; ++r) bb_l[g * 4 + r][i] *= inv;
  }
  __syncthreads();

  // ---- pack c to bf16 (cm_l), 256 threads x 4 elems ----
  {
    int n = tid >> 3, q = tid & 7;
    const float4 cv = *(const float4*)&bb_l[n][q * 4];
    *(uint2*)&cm_l[n][q * 4] = make_uint2(packbf2(cv.x, cv.y), packbf2(cv.z, cv.w));
  }
  __syncthreads();

  // ---- phase B: D[n,c] = sum_i c[n,i] u[i,c]; K=32 -> 1 MFMA/tile ----
  unsigned short* pvs = &t_l[0][0];
  {
    const int mt = w & 1;                  // ncap tile (0..1)
    const bf16x8 af = *(const bf16x8*)&cm_l[mt * 16 + mrow][quad * 8];
#pragma unroll
    for (int j = 0; j < 8; ++j) {
      const int ct = (w >> 1) * 8 + j;     // c tile (0..15)
      const bf16x8 bfv = *(const bf16x8*)&u_t[ct * 16 + mrow][quad * 8];
      f32x4 d = {0.f, 0.f, 0.f, 0.f};
      d = __builtin_amdgcn_mfma_f32_16x16x32_bf16(af, bfv, d, 0, 0, 0);
#pragma unroll
      for (int r = 0; r < 4; ++r)
        pvs[(size_t)(mt * 16 + quad * 4 + r) * 264 + ct * 16 + mrow] =
            packbf1(d[r]);
    }
  }
  __syncthreads();
  {  // coalesced pvb store: thread (rg=tid>>5, co=tid&31); rows rg+8k
    unsigned short* pb = pvb + (size_t)((b * 32 + itile) * Nn) * Cn;
    const int rg = tid >> 5, co = tid & 31;
#pragma unroll
    for (int k = 0; k < 4; ++k) {
      int row = rg + k * 8;
      const uint4 v = *(const uint4*)&pvs[(size_t)row * 264 + co * 8];
      *(uint4*)&pb[(size_t)row * Cn + co * 8] = v;
    }
  }

  // ---- last-arrival protocol: 8 per-b counters (one per 4-n group) ----
  __syncthreads();                 // drains vmcnt -> pv stores at L2
  if (tid == 0) {
    __threadfence();               // L2 writeback to device coherent point
    unsigned int m = 0;
#pragma unroll
    for (int g = 0; g < 8; ++g)
      if (atomicAdd(&cnt[b * 8 + g], 1u) == 31u) m |= (1u << g);
    gmask = m;
  }
  __syncthreads();
  const unsigned int mask = gmask;
  if (mask == 0) return;           // block-uniform
  __threadfence();                 // acquire: invalidate stale L1/L2

  // ---- sst tail: wave w handles n = g*4 + w ----
  for (int g = 0; g < 8; ++g) {
    if (!(mask & (1u << g))) continue;
    const int n = g * 4 + w;
    {  // T1: v[c] = sum over 32 it-slabs (coalesced 512 B/wave per it)
      const unsigned short* p =
          pvb + ((size_t)(b * 32) * 32 + n) * 256 + lane * 4;
      float a0 = 0.f, a1 = 0.f, a2 = 0.f, a3 = 0.f;
#pragma unroll
      for (int it = 0; it < 32; ++it) {
        uint2 r = *(const uint2*)&p[(size_t)it * 8192];
        a0 += bfu((unsigned short)(r.x & 0xffffu));
        a1 += bfu((unsigned short)(r.x >> 16));
        a2 += bfu((unsigned short)(r.y & 0xffffu));
        a3 += bfu((unsigned short)(r.y >> 16));
      }
      vvL[w][lane * 4 + 0] = a0; vvL[w][lane * 4 + 1] = a1;
      vvL[w][lane * 4 + 2] = a2; vvL[w][lane * 4 + 3] = a3;
    }
    __syncthreads();
    {  // T2: s[d] = sum_c v[c] Wbf[c][n*64+d]; lane (dg=ln&7 -> 8d, cg=ln>>3)
      const int dg = lane & 7, cg = lane >> 3;
      float acc[8];
#pragma unroll
      for (int e = 0; e < 8; ++e) acc[e] = 0.f;
      const unsigned short* wp =
          Wbf + (size_t)(cg * 32) * ND + (size_t)n * Dn + dg * 8;
#pragma unroll
      for (int j = 0; j < 32; ++j) {
        union { bf16x8 v; unsigned short us[8]; } wv8;
        wv8.v = *(const bf16x8*)&wp[(size_t)j * ND];
        const float vc = vvL[w][cg * 32 + j];
#pragma unroll
        for (int e = 0; e < 8; ++e) acc[e] += vc * bfu(wv8.us[e]);
      }
#pragma unroll
      for (int off = 8; off <= 32; off <<= 1)
#pragma unroll
        for (int e = 0; e < 8; ++e) acc[e] += __shfl_xor(acc[e], off, 64);
      float sq = 0.f;
#pragma unroll
      for (int e = 0; e < 8; ++e) sq += acc[e] * acc[e];
#pragma unroll
      for (int off = 1; off <= 4; off <<= 1) sq += __shfl_xor(sq, off, 64);
      const float inv = 1.0f / sqrtf(sq + 1e-7f);
      if (cg == 0) {
#pragma unroll
        for (int e = 0; e < 8; ++e) {
          float o = acc[e] * inv;
          olL[w][dg * 8 + e] = o;
          if (outp) outp[((size_t)(b * 32 + n)) * 64 + dg * 8 + e] = o;
        }
      }
    }
    __syncthreads();
    if (writeT) {  // T3: t[c] = sum_d o[d] WbfT[n*64+d][c]; 512 B/wave per d
      float a[4];
#pragma unroll
      for (int e = 0; e < 4; ++e) a[e] = 0.f;
      const unsigned short* wt = WbfT + ((size_t)(n * 64)) * Cn + lane * 4;
#pragma unroll
      for (int d = 0; d < 64; ++d) {
        uint2 r = *(const uint2*)&wt[(size_t)d * Cn];
        const float od = olL[w][d];
        a[0] += od * bfu((unsigned short)(r.x & 0xffffu));
        a[1] += od * bfu((unsigned short)(r.x >> 16));
        a[2] += od * bfu((unsigned short)(r.y & 0xffffu));
        a[3] += od * bfu((unsigned short)(r.y >> 16));
      }
      *(uint2*)&t16_out[((size_t)(b * 32 + n)) * Cn + lane * 4] = make_uint2(
          ((unsigned int)packbf1(a[0])) | ((unsigned int)packbf1(a[1]) << 16),
          ((unsigned int)packbf1(a[2])) | ((unsigned int)packbf1(a[3]) << 16));
    }
    __syncthreads();  // before next g reuses vvL/olL
  }
}

extern "C" void kernel_launch(void* const* d_in, const int* in_sizes, int n_in,
                              void* d_out, int out_size, void* d_ws, size_t ws_size,
                              hipStream_t stream) {
  (void)in_sizes; (void)n_in; (void)out_size; (void)ws_size;
  const float* u = (const float*)d_in[0];   // (32,1024,256)
  const float* W = (const float*)d_in[1];   // (256,2048)
  float* out = (float*)d_out;               // (32,32,64)
  float* ws = (float*)d_ws;
  // ws layout (float units): pvb bf16 4194304 | psu 262144 | Wbf 262144 |
  // WbfT 262144 | tb16 262144 | ub16 4194304 | cnt 512 uints (128 floats)
  unsigned short* pvb  = (unsigned short*)ws;
  float*          psu  = ws + 4194304;
  unsigned short* Wbf  = (unsigned short*)(ws + 4456448);
  unsigned short* WbfT = (unsigned short*)(ws + 4718592);
  unsigned short* tb16 = (unsigned short*)(ws + 4980736);
  unsigned short* ub16 = (unsigned short*)(ws + 5242880);
  unsigned int*   cnt  = (unsigned int*)(ws + 9437184);  // [0..255]=A, [256..511]=B

  k_pre<<<1280, 256, 0, stream>>>(u, W, psu, Wbf, WbfT, ub16, cnt);
  // iter 0: v0 = colsum/32 (same v for all n of a b)
  k_sst<<<1024, 256, 0, stream>>>(psu, 1.0f / 32.0f, Wbf, WbfT, tb16);
  // iter 1: route + fused sst tail (writes tb16)
  k_route_f<<<dim3(32, 32), 256, 0, stream>>>(tb16, ub16, pvb, Wbf, WbfT,
                                              tb16, nullptr, 1, cnt);
  // iter 2 (final): route + fused sst tail (writes out)
  k_route_f<<<dim3(32, 32), 256, 0, stream>>>(tb16, ub16, pvb, Wbf, WbfT,
                                              nullptr, out, 0, cnt + 256);
}

// Round 4
// 127.573 us; speedup vs baseline: 2.1969x; 2.1969x over previous
//
#include <hip/hip_runtime.h>
#include <math.h>

// Capsule routing, u_hat never materialized (factors through W):
//   v[b,n,c] = sum_i c[b,n,i] u[b,i,c]
//   s[b,n,d] = sum_c v[b,n,c] W[c,n*64+d];  o = squash(s)
//   t[b,n,c] = sum_d o[b,n,d] W[c,n*64+d]
//   b[b,n,i] = sum_c t[b,n,c] u[b,i,c]
// Iter 0: b=0 -> c uniform 1/32 -> v0 = colsum(u)/32.
//
// R13: revert R12's fused last-arrival protocol (per-block __threadfence on
// gfx950 = L2 writeback storm across non-coherent XCD L2s; k_route_f was
// 111us with VALUBusy 3.6% -> ~107us stall). Back to R11's 6-launch shape.
// All kernels are latency-bound (VALUBusy <5%), so this round cuts serial
// phase depth:
//  - k_sst at 512 threads: phase depths halved (1a: 2 rows, ph2/ph3: 4
//    iters), LDS ~19KB -> 4 blocks x 8 waves = 32 waves/CU (FULL occupancy),
//    grid 1024 = exactly one block-round on 256 CUs. Runs 3x.
//  - k_route: bf16 c-pack folded into softmax tail (one fewer phase+sync).
// Carried: ub16 precast, bf16 W both layouts, bf16 pv + bf16 t, MFMA route,
// no grid.sync (R4: ~1000us spin), no in-kernel device fences (R12 lesson).

constexpr int Bn = 32, In = 1024, Cn = 256, Nn = 32, Dn = 64, ND = 2048;

typedef __attribute__((ext_vector_type(8))) short bf16x8;
typedef __attribute__((ext_vector_type(4))) float f32x4;

__device__ __forceinline__ unsigned int packbf2(float a, float b) {
  unsigned int xa = __float_as_uint(a), xb = __float_as_uint(b);
  xa = (xa + 0x7fffu + ((xa >> 16) & 1u)) >> 16;  // RNE
  xb = (xb + 0x7fffu + ((xb >> 16) & 1u)) >> 16;
  return xa | (xb << 16);
}
__device__ __forceinline__ unsigned short packbf1(float a) {
  unsigned int x = __float_as_uint(a);
  return (unsigned short)((x + 0x7fffu + ((x >> 16) & 1u)) >> 16);
}
__device__ __forceinline__ float bfu(unsigned short us) {
  return __uint_as_float((unsigned int)us << 16);
}

// ---- k_pre: colsum+ucast (z<1024) | WbfT transpose (1024..1151) | Wbf cast -
__global__ __launch_bounds__(256) void k_pre(
    const float* __restrict__ u, const float* __restrict__ W,
    float* __restrict__ psu, unsigned short* __restrict__ Wbf,
    unsigned short* __restrict__ WbfT, unsigned short* __restrict__ ub16) {
  const int z = blockIdx.x, tid = threadIdx.x;
  if (z < 1024) {  // colsum: psu[z*256+c] = sum over 32 i of u[b, ch*32+i, c]
    int b = z >> 5, ch = z & 31;
    const float* up = u + ((size_t)(b * In + ch * 32)) * Cn + tid;
    unsigned short* ubp = ub16 + ((size_t)(b * In + ch * 32)) * Cn + tid;
    float s = 0.f;
#pragma unroll 8
    for (int j = 0; j < 32; ++j) {
      float v = up[(size_t)j * Cn];
      s += v;
      ubp[(size_t)j * Cn] = packbf1(v);  // bf16 u copy, coalesced 512B rows
    }
    psu[(size_t)z * Cn + tid] = s;
  } else if (z < 1152) {  // WbfT[nd][c] = bf16(W[c][nd]), 64x64 tiles
    __shared__ float tile[64][65];
    int t = z - 1024;
    int x0 = (t & 31) * 64, y0 = (t >> 5) * 64;  // x=nd, y=c
    int lx = tid & 63, ly = tid >> 6;
#pragma unroll
    for (int k = 0; k < 16; ++k) {
      int y = ly + k * 4;
      tile[y][lx] = W[(size_t)(y0 + y) * ND + x0 + lx];
    }
    __syncthreads();
#pragma unroll
    for (int k = 0; k < 8; ++k) {  // 64 rows x 32 uints
      int idx = tid + k * 256;
      int row = idx >> 5, cu = idx & 31;
      unsigned int v = packbf2(tile[2 * cu][row], tile[2 * cu + 1][row]);
      *(unsigned int*)&WbfT[(size_t)(x0 + row) * Cn + y0 + 2 * cu] = v;
    }
  } else {  // Wbf: straight cast, 128 blocks x 4096 floats
    int zb = z - 1152;
    const float* src = W + (size_t)zb * 4096;
    unsigned short* dst = Wbf + (size_t)zb * 4096;
#pragma unroll
    for (int k = 0; k < 4; ++k) {
      int off = k * 1024 + tid * 4;
      const float4 v = *(const float4*)&src[off];
      *(uint2*)&dst[off] = make_uint2(packbf2(v.x, v.y), packbf2(v.z, v.w));
    }
  }
}

// ---- fused: v-reduce -> s -> squash -> [out] -> [t]; 512 threads -----------
// 8 waves/block, ~19KB LDS -> 4 blocks/CU = 32 waves/CU (full occupancy);
// grid 1024 = one block-round on 256 CUs. Phase depths halved vs 256-thr.
__global__ __launch_bounds__(512) void k_sst(
    const void* __restrict__ src, int srcBf16, long bS, long nS, long cS,
    float scale, const unsigned short* __restrict__ Wbf,
    const unsigned short* __restrict__ WbfT, unsigned short* __restrict__ tb,
    float* __restrict__ outp, int writeT) {
  int bn = blockIdx.x, b = bn >> 5, n = bn & 31;
  int tid = threadIdx.x;
  __shared__ float vs[Cn];
  __shared__ float ol[Dn];
  __shared__ float scr[4352];  // ph1/3: [16][272]; ph2: [64][68]
  {  // phase 1a: v partials. thread (g=tid>>5 -> 2 ch, co=tid&31 -> 8 c)
    const int g = tid >> 5, co = tid & 31;
    float acc[8];
#pragma unroll
    for (int e = 0; e < 8; ++e) acc[e] = 0.f;
    if (srcBf16) {
      const unsigned short* p =
          (const unsigned short*)src + b * bS + n * nS + co * 8;
#pragma unroll
      for (int k = 0; k < 2; ++k) {
        union { bf16x8 v; unsigned short us[8]; } w;
        w.v = *(const bf16x8*)&p[(size_t)(g * 2 + k) * cS];
#pragma unroll
        for (int e = 0; e < 8; ++e) acc[e] += bfu(w.us[e]);
      }
    } else {
      const float* p = (const float*)src + b * bS + n * nS + co * 8;
#pragma unroll
      for (int k = 0; k < 2; ++k) {
        const float4 v0 = *(const float4*)&p[(size_t)(g * 2 + k) * cS];
        const float4 v1 = *(const float4*)&p[(size_t)(g * 2 + k) * cS + 4];
        acc[0] += v0.x; acc[1] += v0.y; acc[2] += v0.z; acc[3] += v0.w;
        acc[4] += v1.x; acc[5] += v1.y; acc[6] += v1.z; acc[7] += v1.w;
      }
    }
    *(float4*)&scr[g * 272 + co * 8] =
        make_float4(acc[0], acc[1], acc[2], acc[3]);
    *(float4*)&scr[g * 272 + co * 8 + 4] =
        make_float4(acc[4], acc[5], acc[6], acc[7]);
  }
  __syncthreads();
  if (tid < 256) {  // phase 1b: vs[c] = sum of 16 partials
    float s = 0.f;
#pragma unroll
    for (int k = 0; k < 16; ++k) s += scr[k * 272 + tid];
    vs[tid] = s * scale;
  }
  __syncthreads();
  {  // phase 2: s partials. thread (cg=tid>>3 -> 4 c, do8=tid&7 -> 8 d)
    const int cg = tid >> 3, do8 = tid & 7;
    const unsigned short* wp =
        Wbf + (size_t)(cg * 4) * ND + (size_t)n * Dn + do8 * 8;
    float acc[8];
#pragma unroll
    for (int e = 0; e < 8; ++e) acc[e] = 0.f;
#pragma unroll
    for (int j = 0; j < 4; ++j) {
      union { bf16x8 v; unsigned short us[8]; } w;
      w.v = *(const bf16x8*)&wp[(size_t)j * ND];
      const float vc = vs[cg * 4 + j];
#pragma unroll
      for (int e = 0; e < 8; ++e) acc[e] += vc * bfu(w.us[e]);
    }
    *(float4*)&scr[cg * 68 + do8 * 8] =
        make_float4(acc[0], acc[1], acc[2], acc[3]);
    *(float4*)&scr[cg * 68 + do8 * 8 + 4] =
        make_float4(acc[4], acc[5], acc[6], acc[7]);
  }
  __syncthreads();
  if (tid < 64) {  // squash (one full wave): sum 64 cg partials per d
    float a = 0.f;
#pragma unroll
    for (int k = 0; k < 64; ++k) a += scr[k * 68 + tid];
    float sq = a * a;
#pragma unroll
    for (int off = 32; off > 0; off >>= 1) sq += __shfl_xor(sq, off, 64);
    float o = a / sqrtf(sq + 1e-7f);
    ol[tid] = o;
    if (outp) outp[(size_t)bn * Dn + tid] = o;
  }
  __syncthreads();
  if (writeT) {  // phase 3: t partials. thread (dg=tid>>5 -> 4 d, co -> 8 c)
    {
      const int dg = tid >> 5, co = tid & 31;
      const unsigned short* wt =
          WbfT + (size_t)(n * Dn + dg * 4) * Cn + co * 8;
      float acc[8];
#pragma unroll
      for (int e = 0; e < 8; ++e) acc[e] = 0.f;
#pragma unroll
      for (int e = 0; e < 4; ++e) {
        union { bf16x8 v; unsigned short us[8]; } w;
        w.v = *(const bf16x8*)&wt[(size_t)e * Cn];
        const float od = ol[dg * 4 + e];
#pragma unroll
        for (int cc = 0; cc < 8; ++cc) acc[cc] += od * bfu(w.us[cc]);
      }
      *(float4*)&scr[dg * 272 + co * 8] =
          make_float4(acc[0], acc[1], acc[2], acc[3]);
      *(float4*)&scr[dg * 272 + co * 8 + 4] =
          make_float4(acc[4], acc[5], acc[6], acc[7]);
    }
    __syncthreads();
    if (tid < 256) {
      float s = 0.f;
#pragma unroll
      for (int k = 0; k < 16; ++k) s += scr[k * 272 + tid];
      tb[(size_t)bn * Cn + tid] = packbf1(s);  // t stored bf16
    }
  }
}

// ---- fused routing step (MFMA): bb = u.t^T -> softmax -> pv = c.u ----------
// Block (b, it): i-tile of 32, 256 threads (4 waves). pv stored bf16.
// t arrives pre-cast bf16; u consumed as pre-cast bf16 (ub16).
__global__ __launch_bounds__(256, 4) void k_route(
    const unsigned short* __restrict__ tbb,
    const unsigned short* __restrict__ ub16,
    unsigned short* __restrict__ pvb) {
  const int b = blockIdx.x, itile = blockIdx.y, i0 = itile * 32;
  const int tid = threadIdx.x;
  const int lane = tid & 63, w = tid >> 6;
  const int mrow = lane & 15, quad = lane >> 4;

  __shared__ unsigned short t_l[32][264];   // bf16; row 528 B; reused as pvs
  __shared__ unsigned short u_t[256][40];   // bf16 i-major; row 80 B
  __shared__ unsigned short cm_l[32][40];   // bf16 softmax(c)
  __shared__ float bb_l[32][36];
  __shared__ float smr[2][8][32];           // softmax partial max / sum

  // ---- stage t (straight bf16 copy) + u_t (bf16 copy, transposed) ----
  {
    const unsigned short* tp = tbb + (size_t)b * Nn * Cn;
#pragma unroll
    for (int k = 0; k < 8; ++k) {
      int idx = tid + k * 256;           // 2048 = 32 rows x 64 quads
      int row = idx >> 6, q = idx & 63;
      *(uint2*)&t_l[row][q * 4] = *(const uint2*)&tp[(size_t)row * Cn + q * 4];
    }
    const int ti = tid & 31, qb = tid >> 5;
    const unsigned short* up = ub16 + ((size_t)(b * In + i0 + ti)) * Cn;
#pragma unroll
    for (int m = 0; m < 4; ++m) {
      int c8 = qb + m * 8;               // chunk of 8 consecutive c
      union { bf16x8 v; unsigned short us[8]; } uv;
      uv.v = *(const bf16x8*)&up[c8 * 8];
#pragma unroll
      for (int e = 0; e < 8; ++e) u_t[c8 * 8 + e][ti] = uv.us[e];
    }
  }
  __syncthreads();

  // ---- phase A: D[i,n] = sum_c u[i,c] t[n,c]; wave tile (i0t, n0t) ----
  {
    const int i0t = (w & 1) * 16, n0t = (w >> 1) * 16;
    const unsigned short* ubp =
        ub16 + ((size_t)(b * In + i0 + i0t + mrow)) * Cn + quad * 8;
    f32x4 acc = {0.f, 0.f, 0.f, 0.f};
#pragma unroll
    for (int k0 = 0; k0 < 8; ++k0) {       // c = k0*32 + quad*8 + j
      const bf16x8 af = *(const bf16x8*)(ubp + k0 * 32);
      const bf16x8 bf = *(const bf16x8*)&t_l[n0t + mrow][k0 * 32 + quad * 8];
      acc = __builtin_amdgcn_mfma_f32_16x16x32_bf16(af, bf, acc, 0, 0, 0);
    }
    // D: col=lane&15 -> n within tile, row=quad*4+reg -> i within tile
#pragma unroll
    for (int r = 0; r < 4; ++r)
      bb_l[n0t + mrow][i0t + quad * 4 + r] = acc[r];
  }
  __syncthreads();

  // ---- softmax over n per i (wave-parallel), pack to cm_l fused in tail ---
  {
    const int i = tid & 31, g = tid >> 5;  // g handles n = g*4 .. g*4+3
    float m4 = fmaxf(fmaxf(bb_l[g * 4 + 0][i], bb_l[g * 4 + 1][i]),
                     fmaxf(bb_l[g * 4 + 2][i], bb_l[g * 4 + 3][i]));
    smr[0][g][i] = m4;
    __syncthreads();
    float m = smr[0][0][i];
#pragma unroll
    for (int k = 1; k < 8; ++k) m = fmaxf(m, smr[0][k][i]);
    float e[4];
    float s4 = 0.f;
#pragma unroll
    for (int r = 0; r < 4; ++r) {
      e[r] = __expf(bb_l[g * 4 + r][i] - m);
      s4 += e[r];
    }
    smr[1][g][i] = s4;
    __syncthreads();
    float ss = 0.f;
#pragma unroll
    for (int k = 0; k < 8; ++k) ss += smr[1][k][i];
    float inv = 1.f / ss;
#pragma unroll
    for (int r = 0; r < 4; ++r) cm_l[g * 4 + r][i] = packbf1(e[r] * inv);
  }
  __syncthreads();

  // ---- phase B: D[n,c] = sum_i c[n,i] u[i,c]; K=32 -> 1 MFMA/tile ----
  // Output staged in LDS (reuse t_l as pvs[32][264]) then coalesced store.
  unsigned short* pvs = &t_l[0][0];
  {
    const int mt = w & 1;                  // ncap tile (0..1)
    const bf16x8 af = *(const bf16x8*)&cm_l[mt * 16 + mrow][quad * 8];
#pragma unroll
    for (int j = 0; j < 8; ++j) {
      const int ct = (w >> 1) * 8 + j;     // c tile (0..15)
      const bf16x8 bfv = *(const bf16x8*)&u_t[ct * 16 + mrow][quad * 8];
      f32x4 d = {0.f, 0.f, 0.f, 0.f};
      d = __builtin_amdgcn_mfma_f32_16x16x32_bf16(af, bfv, d, 0, 0, 0);
      // D: col=lane&15 -> c within tile, row=quad*4+reg -> ncap within tile
#pragma unroll
      for (int r = 0; r < 4; ++r)
        pvs[(size_t)(mt * 16 + quad * 4 + r) * 264 + ct * 16 + mrow] =
            packbf1(d[r]);
    }
  }
  __syncthreads();
  {  // coalesced pvb store: thread (rg=tid>>5, co=tid&31); rows rg+8k
    unsigned short* pb = pvb + (size_t)((b * 32 + itile) * Nn) * Cn;
    const int rg = tid >> 5, co = tid & 31;
#pragma unroll
    for (int k = 0; k < 4; ++k) {
      int row = rg + k * 8;
      const uint4 v = *(const uint4*)&pvs[(size_t)row * 264 + co * 8];
      *(uint4*)&pb[(size_t)row * Cn + co * 8] = v;
    }
  }
}

extern "C" void kernel_launch(void* const* d_in, const int* in_sizes, int n_in,
                              void* d_out, int out_size, void* d_ws, size_t ws_size,
                              hipStream_t stream) {
  (void)in_sizes; (void)n_in; (void)out_size; (void)ws_size;
  const float* u = (const float*)d_in[0];   // (32,1024,256)
  const float* W = (const float*)d_in[1];   // (256,2048)
  float* out = (float*)d_out;               // (32,32,64)
  float* ws = (float*)d_ws;
  // ws layout (float units): pvb bf16 4194304 | psu 262144 | Wbf 262144 |
  // WbfT 262144 | tb16 262144 | ub16 4194304  => 36 MB total.
  unsigned short* pvb  = (unsigned short*)ws;
  float*          psu  = ws + 4194304;
  unsigned short* Wbf  = (unsigned short*)(ws + 4456448);
  unsigned short* WbfT = (unsigned short*)(ws + 4718592);
  unsigned short* tb16 = (unsigned short*)(ws + 4980736);
  unsigned short* ub16 = (unsigned short*)(ws + 5242880);

  k_pre<<<1280, 256, 0, stream>>>(u, W, psu, Wbf, WbfT, ub16);
  // iter 0: v0 = colsum/32 (psu fp32: b-stride 8192, ch-stride 256)
  k_sst<<<1024, 512, 0, stream>>>(psu, 0, 8192L, 0L, 256L, 1.0f / 32.0f,
                                  Wbf, WbfT, tb16, nullptr, 1);
  // iter 1
  k_route<<<dim3(32, 32), 256, 0, stream>>>(tb16, ub16, pvb);
  // pvb bf16: b-stride 262144, n-stride 256, ch(it)-stride 8192 (ushorts)
  k_sst<<<1024, 512, 0, stream>>>(pvb, 1, 262144L, 256L, 8192L, 1.0f,
                                  Wbf, WbfT, tb16, nullptr, 1);
  // iter 2 (final)
  k_route<<<dim3(32, 32), 256, 0, stream>>>(tb16, ub16, pvb);
  k_sst<<<1024, 512, 0, stream>>>(pvb, 1, 262144L, 256L, 8192L, 1.0f,
                                  Wbf, WbfT, tb16, out, 0);
}